// Round 9
// baseline (456.718 us; speedup 1.0000x reference)
//
#include <hip/hip_runtime.h>
#include <hip/hip_bf16.h>

constexpr int B = 4, N = 8192, S = 2048;

typedef __attribute__((ext_vector_type(8))) short short8;
typedef __attribute__((ext_vector_type(4))) float v4f;

__device__ inline float u2f(ushort u) {
    union { ushort u; __hip_bfloat16 h; } c; c.u = u; return __bfloat162float(c.h);
}
__device__ inline ushort f2u(float f) {
    union { ushort u; __hip_bfloat16 h; } c; c.h = __float2bfloat16(f); return c.u;
}
__device__ inline void async_lds16(const void* g, void* l) {
    __builtin_amdgcn_global_load_lds(
        (const __attribute__((address_space(1))) unsigned*)g,
        (__attribute__((address_space(3))) unsigned*)l, 16, 0, 0);
}
__device__ inline short8 ld8(const ushort* p) { return *(const short8*)p; }

// ---- transpose helper: 256 logical threads (tt), shared barrier with caller
__device__ inline void transpose_tile(
    const float* __restrict__ ip, ushort* __restrict__ op,
    int L, int C, int l0, int c0, int tt, ushort (*tl)[66])
{
    const int lr = tt & 63, cb = tt >> 6;
    #pragma unroll
    for (int i = 0; i < 16; ++i) {
        int c = cb + 4 * i;
        tl[lr][c] = f2u(ip[(size_t)(c0 + c) * L + l0 + lr]);
    }
    __syncthreads();
    const int cp = tt & 31, lrow = tt >> 5;
    #pragma unroll
    for (int i = 0; i < 8; ++i) {
        int l = lrow + 8 * i;
        ushort2 v;
        v.x = tl[l][2 * cp]; v.y = tl[l][2 * cp + 1];
        *(ushort2*)(op + (size_t)(l0 + l) * C + c0 + 2 * cp) = v;
    }
}

// ---- prep_all: 3-NN (VALU blocks) overlapped with transposes/packs (mem) --
__global__ __launch_bounds__(512) void prep_all(
    const float* __restrict__ W1, const float* __restrict__ W2,
    const float* __restrict__ pos2, const float* __restrict__ f2,
    const float* __restrict__ f1, const float* __restrict__ pos1,
    ushort* __restrict__ W1r, ushort* __restrict__ W2r,
    float* __restrict__ zero_region,
    ushort* __restrict__ f2T, ushort* __restrict__ f1T,
    float* __restrict__ wgt, int* __restrict__ idxb)
{
    __shared__ __align__(16) char sm[45056];
    const int bid = blockIdx.x;
    const int t = threadIdx.x;

    if (bid < 512) {
        float4* pk = (float4*)sm;
        float*  dL = (float*)(sm + 32768);
        int*    iL = (int*)  (sm + 32768 + 6144);
        const int b = bid >> 7, n0 = (bid & 127) * 64;
        const int lane = t & 63;
        const int w = __builtin_amdgcn_readfirstlane(t >> 6);

        for (int i = t; i < S; i += 512) {
            float x = pos2[(b * 3 + 0) * S + i];
            float y = pos2[(b * 3 + 1) * S + i];
            float z = pos2[(b * 3 + 2) * S + i];
            pk[i] = make_float4(x, y, z, x * x + y * y + z * z);
        }
        __syncthreads();

        {
            const int qi = n0 + lane;
            const float x1 = pos1[(b * 3 + 0) * N + qi];
            const float y1 = pos1[(b * 3 + 1) * N + qi];
            const float z1 = pos1[(b * 3 + 2) * N + qi];
            const float t1 = x1 * x1 + y1 * y1 + z1 * z1;
            const float4* __restrict__ pp = pk + w * 256;
            float d0 = 3.4e38f, d1 = 3.4e38f, d2 = 3.4e38f;
            int i0 = 0x7fffffff, i1 = 0x7fffffff, i2 = 0x7fffffff;
            #pragma unroll 8
            for (int i = 0; i < 256; ++i) {
                float4 p = pp[i];
                float dot = fmaf(x1, p.x, fmaf(y1, p.y, z1 * p.z));
                float dd = fmaf(-2.f, dot, t1) + p.w;
                int s = w * 256 + i;
                bool c0 = dd < d0, c1 = dd < d1, c2 = dd < d2;
                i2 = c1 ? i1 : (c2 ? s : i2);
                i1 = c0 ? i0 : (c1 ? s : i1);
                i0 = c0 ? s : i0;
                float nd1 = __builtin_amdgcn_fmed3f(dd, d0, d1);
                float nd2 = __builtin_amdgcn_fmed3f(dd, d1, d2);
                d0 = fminf(d0, dd);
                d1 = nd1; d2 = nd2;
            }
            int base = (w * 64 + lane) * 3;
            dL[base + 0] = d0; dL[base + 1] = d1; dL[base + 2] = d2;
            iL[base + 0] = i0; iL[base + 1] = i1; iL[base + 2] = i2;
        }
        __syncthreads();
        if (t < 64) {
            float f0 = dL[t*3+0], fv1 = dL[t*3+1], fv2 = dL[t*3+2];
            int   j0 = iL[t*3+0], j1 = iL[t*3+1], j2 = iL[t*3+2];
            #pragma unroll
            for (int c = 1; c < 8; ++c) {
                int cb = (c * 64 + t) * 3;
                #pragma unroll
                for (int k = 0; k < 3; ++k) {
                    float d = dL[cb + k]; int id = iL[cb + k];
                    bool l0 = (d < f0)  || (d == f0  && id < j0);
                    bool l1 = (d < fv1) || (d == fv1 && id < j1);
                    bool l2 = (d < fv2) || (d == fv2 && id < j2);
                    if (l0)      { fv2 = fv1; j2 = j1; fv1 = f0; j1 = j0; f0 = d; j0 = id; }
                    else if (l1) { fv2 = fv1; j2 = j1; fv1 = d; j1 = id; }
                    else if (l2) { fv2 = d; j2 = id; }
                }
            }
            float w0 = 1.f / fmaxf(f0, 1e-10f);
            float w1 = 1.f / fmaxf(fv1, 1e-10f);
            float w2 = 1.f / fmaxf(fv2, 1e-10f);
            float inv = 1.f / (w0 + w1 + w2);
            j0 = ((unsigned)j0 < S) ? j0 : 0;
            j1 = ((unsigned)j1 < S) ? j1 : 0;
            j2 = ((unsigned)j2 < S) ? j2 : 0;
            int base = (b * N + n0 + t) * 3;
            wgt[base + 0] = w0 * inv; wgt[base + 1] = w1 * inv; wgt[base + 2] = w2 * inv;
            idxb[base + 0] = j0; idxb[base + 1] = j1; idxb[base + 2] = j2;
        }
    } else if (bid < 768) {                // f2: [B,256,S] -> [B,S,256] bf16
        ushort (*tl)[66] = (ushort(*)[66])(sm + (t >> 8) * 16896);
        const int tt = t & 255;
        int tile = (bid - 512) * 2 + (t >> 8);
        int b = tile >> 7, ct = (tile >> 5) & 3, st = tile & 31;
        transpose_tile(f2 + (size_t)b * 256 * S, f2T + (size_t)b * S * 256,
                       S, 256, st * 64, ct * 64, tt, tl);
    } else if (bid < 1280) {               // f1: [B,128,N] -> [B,N,128] bf16
        ushort (*tl)[66] = (ushort(*)[66])(sm + (t >> 8) * 16896);
        const int tt = t & 255;
        int u = (bid - 768) * 2 + (t >> 8);
        int b = u >> 8, ct = (u >> 7) & 1, lt = u & 127;
        transpose_tile(f1 + (size_t)b * 128 * N, f1T + (size_t)b * N * 128,
                       N, 128, lt * 64, ct * 64, tt, tl);
    } else {
        int i = (bid - 1280) * 512 + t;
        if (i < 12288) {
            int kk = i >> 10, qq = (i >> 8) & 3, o = i & 255;
            const float* src = W1 + o * 384 + kk * 32 + qq * 8;
            float4 a = *(const float4*)src, bb = *(const float4*)(src + 4);
            union { short8 s; ushort u[8]; } pkv;
            pkv.u[0]=f2u(a.x); pkv.u[1]=f2u(a.y); pkv.u[2]=f2u(a.z); pkv.u[3]=f2u(a.w);
            pkv.u[4]=f2u(bb.x); pkv.u[5]=f2u(bb.y); pkv.u[6]=f2u(bb.z); pkv.u[7]=f2u(bb.w);
            *(short8*)(W1r + i * 8) = pkv.s;
        } else if (i < 20480) {
            int u = i - 12288;
            int kk = u >> 10, qq = (u >> 8) & 3, o = u & 255;
            const float* src = W2 + o * 256 + kk * 32 + qq * 8;
            float4 a = *(const float4*)src, bb = *(const float4*)(src + 4);
            union { short8 s; ushort u[8]; } pkv;
            pkv.u[0]=f2u(a.x); pkv.u[1]=f2u(a.y); pkv.u[2]=f2u(a.z); pkv.u[3]=f2u(a.w);
            pkv.u[4]=f2u(bb.x); pkv.u[5]=f2u(bb.y); pkv.u[6]=f2u(bb.z); pkv.u[7]=f2u(bb.w);
            *(short8*)(W2r + u * 8) = pkv.s;
        } else if (i < 21536) {            // zero sums (1024 f32) + ctrs
            zero_region[i - 20480] = 0.f;
        }
    }
}

// ---- mega: GEMM1(K-split) -> spin -> BN1 -> GEMM2 -> spin -> BN2+out -----
// 512 blocks x 512 thr, 52 KB LDS -> >=2 blocks/CU with large margin
// (104 KB of 160 KB; R6's 160KB-exact fit is the suspected deadlock cause).
// launch_bounds(512,4) hard-caps VGPR at 128 so occupancy can't drop below
// 2 blocks/CU. 512 blocks <= 512 guaranteed slots -> spin barrier safe.
// y1/y2 live in LDS: y never touches HBM.
__global__ __launch_bounds__(512, 4) void mega_kernel(
    const ushort* __restrict__ W1r, const float* __restrict__ bias1,
    const ushort* __restrict__ f2T, const ushort* __restrict__ f1T,
    const int* __restrict__ idxb, const float* __restrict__ wgt,
    float* __restrict__ sums, unsigned* __restrict__ ctrs,
    const float* __restrict__ g1, const float* __restrict__ be1,
    const ushort* __restrict__ W2r, const float* __restrict__ bias2,
    const float* __restrict__ g2, const float* __restrict__ be2,
    float* __restrict__ out)
{
    __shared__ __align__(16) char smem[53248];    // 52 KB
    ushort* Xs   = (ushort*)smem;                 // [0,32K) staging / Y-tile
    ushort* Y    = (ushort*)smem;
    ushort* Wb   = (ushort*)(smem + 32768);       // [32K,48K) one W chunk
    float*  stat = (float*)(smem + 49152);        // [48K,50K) 512 f32
    float*  aux  = (float*)(smem + 51200);        // [50K,52K) 512 f32
    float*  tl2  = (float*)(smem + 32768);        // [32K,48.3K) 64x65 f32

    const int t = threadIdx.x;
    const int lane = t & 63;
    const int w = __builtin_amdgcn_readfirstlane(t >> 6);  // 0..7
    const int b = blockIdx.y;
    const int n0 = blockIdx.x * 64;
    const int q = lane >> 4, r = lane & 15, r7 = r & 7;

    // W1 chunk0 -> LDS (async; drains at first barrier)
    #pragma unroll
    for (int jj = 0; jj < 2; ++jj)
        async_lds16((const char*)W1r + jj * 8192 + t * 16,
                    (char*)Wb + jj * 8192 + w * 1024);

    // f1 half -> registers (written to LDS at pass boundary)
    short8 f1v[2];
    const int flp = t & 15, fro = t >> 4;                  // fro 0..31
    #pragma unroll
    for (int it = 0; it < 2; ++it)
        f1v[it] = ld8(f1T + ((size_t)b * N + n0 + fro + 32 * it) * 128 + 8 * flp);

    // ---- pass-A staging: fused interp into Xs (stride 256) ----
    {
        const int lp = t & 31, ro = t >> 5;                // ro 0..15
        #pragma unroll
        for (int it = 0; it < 4; ++it) {
            int rr = ro + 16 * it;
            int base = (b * N + n0 + rr) * 3;
            int s0 = idxb[base], s1 = idxb[base + 1], s2 = idxb[base + 2];
            s0 = ((unsigned)s0 < S) ? s0 : 0;
            s1 = ((unsigned)s1 < S) ? s1 : 0;
            s2 = ((unsigned)s2 < S) ? s2 : 0;
            float w0 = wgt[base], w1 = wgt[base + 1], w2 = wgt[base + 2];
            union { short8 s; ushort u[8]; } a, c, d, o;
            a.s = ld8(f2T + ((size_t)b * S + s0) * 256 + 8 * lp);
            c.s = ld8(f2T + ((size_t)b * S + s1) * 256 + 8 * lp);
            d.s = ld8(f2T + ((size_t)b * S + s2) * 256 + 8 * lp);
            #pragma unroll
            for (int j = 0; j < 8; ++j)
                o.u[j] = f2u(w0 * u2f(a.u[j]) + w1 * u2f(c.u[j]) + w2 * u2f(d.u[j]));
            *(short8*)(Xs + rr * 256 + ((lp ^ (rr & 7)) * 8)) = o.s;
        }
    }
    __syncthreads();   // staging + W chunk0 ready

    v4f acc[2][4];
    #pragma unroll
    for (int mt = 0; mt < 2; ++mt)
        #pragma unroll
        for (int nf = 0; nf < 4; ++nf) acc[mt][nf] = (v4f){0.f, 0.f, 0.f, 0.f};

    // ---- GEMM1 pass A: chunks 0..7 over interp channels ----
    #pragma unroll
    for (int kk = 0; kk < 8; ++kk) {
        short8 wreg0 = ld8(W1r + (kk + 1) * 8192 + t * 16);
        short8 wreg1 = ld8(W1r + (kk + 1) * 8192 + t * 16 + 8);
        short8 af[2], bf[4];
        #pragma unroll
        for (int mt = 0; mt < 2; ++mt)
            af[mt] = ld8(Wb + q * 2048 + (w * 32 + mt * 16 + r) * 8);
        #pragma unroll
        for (int nf = 0; nf < 4; ++nf)
            bf[nf] = ld8(Xs + (nf * 16 + r) * 256 + (((kk * 4 + q) ^ r7) * 8));
        #pragma unroll
        for (int mt = 0; mt < 2; ++mt)
            #pragma unroll
            for (int nf = 0; nf < 4; ++nf)
                acc[mt][nf] = __builtin_amdgcn_mfma_f32_16x16x32_bf16(
                    af[mt], bf[nf], acc[mt][nf], 0, 0, 0);
        __syncthreads();
        *(short8*)(Wb + t * 16) = wreg0;
        *(short8*)(Wb + t * 16 + 8) = wreg1;
        if (kk == 7) {
            #pragma unroll
            for (int it = 0; it < 2; ++it) {
                int rr = fro + 32 * it;
                *(short8*)(Xs + rr * 128 + ((flp ^ (rr & 7)) * 8)) = f1v[it];
            }
        }
        __syncthreads();
    }

    // ---- GEMM1 pass B: chunks 8..11 over f1 channels ----
    #pragma unroll
    for (int kk = 8; kk < 12; ++kk) {
        short8 wreg0, wreg1;
        if (kk < 11) {
            wreg0 = ld8(W1r + (kk + 1) * 8192 + t * 16);
            wreg1 = ld8(W1r + (kk + 1) * 8192 + t * 16 + 8);
        }
        short8 af[2], bf[4];
        #pragma unroll
        for (int mt = 0; mt < 2; ++mt)
            af[mt] = ld8(Wb + q * 2048 + (w * 32 + mt * 16 + r) * 8);
        #pragma unroll
        for (int nf = 0; nf < 4; ++nf)
            bf[nf] = ld8(Xs + (nf * 16 + r) * 128 + ((((kk - 8) * 4 + q) ^ r7) * 8));
        #pragma unroll
        for (int mt = 0; mt < 2; ++mt)
            #pragma unroll
            for (int nf = 0; nf < 4; ++nf)
                acc[mt][nf] = __builtin_amdgcn_mfma_f32_16x16x32_bf16(
                    af[mt], bf[nf], acc[mt][nf], 0, 0, 0);
        if (kk < 11) {
            __syncthreads();
            *(short8*)(Wb + t * 16) = wreg0;
            *(short8*)(Wb + t * 16 + 8) = wreg1;
            __syncthreads();
        }
    }
    __syncthreads();   // Xs/Wb reads done -> safe to overwrite

    // W2 chunk0 prefetch (overlaps epilogue + barrier wait)
    #pragma unroll
    for (int jj = 0; jj < 2; ++jj)
        async_lds16((const char*)W2r + jj * 8192 + t * 16,
                    (char*)Wb + jj * 8192 + w * 1024);

    // ---- epilogue 1: y-tile -> LDS (swizzled), stats -> sums ----
    #pragma unroll
    for (int mt = 0; mt < 2; ++mt) {
        int ob = w * 32 + mt * 16 + q * 4;
        int g = ob >> 3, e = ob & 7;
        float4 bi = *(const float4*)(bias1 + ob);
        float sj0 = 0, sj1 = 0, sj2 = 0, sj3 = 0;
        float qj0 = 0, qj1 = 0, qj2 = 0, qj3 = 0;
        #pragma unroll
        for (int nf = 0; nf < 4; ++nf) {
            int n = nf * 16 + r;                           // local row
            float v0 = acc[mt][nf][0] + bi.x, v1 = acc[mt][nf][1] + bi.y;
            float v2 = acc[mt][nf][2] + bi.z, v3 = acc[mt][nf][3] + bi.w;
            ushort4 pk; pk.x = f2u(v0); pk.y = f2u(v1); pk.z = f2u(v2); pk.w = f2u(v3);
            *(ushort4*)(Y + n * 256 + ((g ^ (n & 7)) * 8 + e)) = pk;
            sj0 += v0; sj1 += v1; sj2 += v2; sj3 += v3;
            qj0 += v0 * v0; qj1 += v1 * v1; qj2 += v2 * v2; qj3 += v3 * v3;
        }
        #pragma unroll
        for (int m = 1; m <= 8; m <<= 1) {
            sj0 += __shfl_xor(sj0, m); sj1 += __shfl_xor(sj1, m);
            sj2 += __shfl_xor(sj2, m); sj3 += __shfl_xor(sj3, m);
            qj0 += __shfl_xor(qj0, m); qj1 += __shfl_xor(qj1, m);
            qj2 += __shfl_xor(qj2, m); qj3 += __shfl_xor(qj3, m);
        }
        if (r == 0) {
            stat[ob + 0] = sj0; stat[ob + 1] = sj1;
            stat[ob + 2] = sj2; stat[ob + 3] = sj3;
            stat[256 + ob + 0] = qj0; stat[256 + ob + 1] = qj1;
            stat[256 + ob + 2] = qj2; stat[256 + ob + 3] = qj3;
        }
    }
    __syncthreads();
    if (t < 256) {
        atomicAdd(&sums[t], stat[t]);
        atomicAdd(&sums[256 + t], stat[256 + t]);
    }
    __threadfence();
    __syncthreads();
    // ---- grid barrier 1 ----
    if (t == 0) {
        __hip_atomic_fetch_add(&ctrs[0], 1u, __ATOMIC_ACQ_REL,
                               __HIP_MEMORY_SCOPE_AGENT);
        while (__hip_atomic_load(&ctrs[0], __ATOMIC_ACQUIRE,
                                 __HIP_MEMORY_SCOPE_AGENT) < 512u)
            __builtin_amdgcn_s_sleep(8);
    }
    __syncthreads();
    __threadfence();

    // ---- BN1 coefficients + in-place BN1+ReLU on the LDS y-tile ----
    if (t < 256) {
        float sv = __hip_atomic_load(&sums[t], __ATOMIC_RELAXED,
                                     __HIP_MEMORY_SCOPE_AGENT);
        float qv = __hip_atomic_load(&sums[256 + t], __ATOMIC_RELAXED,
                                     __HIP_MEMORY_SCOPE_AGENT);
        float mean = sv * (1.f / 32768.f);
        float var = qv * (1.f / 32768.f) - mean * mean;
        float rstd = rsqrtf(var + 1e-5f);
        float sc = g1[t] * rstd;
        aux[t] = sc;
        aux[256 + t] = be1[t] - mean * sc;
    }
    __syncthreads();
    {
        const int g = t & 31, nb = t >> 5;                // nb 0..15
        float sa[8], sb[8];
        #pragma unroll
        for (int j = 0; j < 8; ++j) {
            sa[j] = aux[g * 8 + j]; sb[j] = aux[256 + g * 8 + j];
        }
        #pragma unroll
        for (int j = 0; j < 4; ++j) {
            int n = nb * 4 + j;                            // rows 0..63
            ushort* p = Y + n * 256 + ((g ^ (n & 7)) * 8);
            union { short8 s; ushort u[8]; } v, o;
            v.s = ld8(p);
            #pragma unroll
            for (int e = 0; e < 8; ++e)
                o.u[e] = f2u(fmaxf(u2f(v.u[e]) * sa[e] + sb[e], 0.f));
            *(short8*)p = o.s;
        }
    }
    __syncthreads();

    // ---- GEMM2 (K=256, 8 chunks), single-buffered W2 + reg prefetch ----
    v4f acc2[2][4];
    #pragma unroll
    for (int mt = 0; mt < 2; ++mt)
        #pragma unroll
        for (int nf = 0; nf < 4; ++nf) acc2[mt][nf] = (v4f){0.f, 0.f, 0.f, 0.f};

    #pragma unroll
    for (int kk = 0; kk < 8; ++kk) {
        short8 wreg0, wreg1;
        if (kk < 7) {
            wreg0 = ld8(W2r + (kk + 1) * 8192 + t * 16);
            wreg1 = ld8(W2r + (kk + 1) * 8192 + t * 16 + 8);
        }
        short8 af[2], bf[4];
        #pragma unroll
        for (int mt = 0; mt < 2; ++mt)
            af[mt] = ld8(Wb + q * 2048 + (w * 32 + mt * 16 + r) * 8);
        #pragma unroll
        for (int nf = 0; nf < 4; ++nf)
            bf[nf] = ld8(Y + (nf * 16 + r) * 256 + (((kk * 4 + q) ^ r7) * 8));
        #pragma unroll
        for (int mt = 0; mt < 2; ++mt)
            #pragma unroll
            for (int nf = 0; nf < 4; ++nf)
                acc2[mt][nf] = __builtin_amdgcn_mfma_f32_16x16x32_bf16(
                    af[mt], bf[nf], acc2[mt][nf], 0, 0, 0);
        if (kk < 7) {
            __syncthreads();
            *(short8*)(Wb + t * 16) = wreg0;
            *(short8*)(Wb + t * 16 + 8) = wreg1;
            __syncthreads();
        }
    }
    __syncthreads();   // Y reads done -> safe to overwrite

    // ---- epilogue 2: y2-tile -> LDS in place, stats -> sums[512..] ----
    #pragma unroll
    for (int mt = 0; mt < 2; ++mt) {
        int ob = w * 32 + mt * 16 + q * 4;
        int g = ob >> 3, e = ob & 7;
        float4 bi = *(const float4*)(bias2 + ob);
        float sj0 = 0, sj1 = 0, sj2 = 0, sj3 = 0;
        float qj0 = 0, qj1 = 0, qj2 = 0, qj3 = 0;
        #pragma unroll
        for (int nf = 0; nf < 4; ++nf) {
            int n = nf * 16 + r;
            float v0 = acc2[mt][nf][0] + bi.x, v1 = acc2[mt][nf][1] + bi.y;
            float v2 = acc2[mt][nf][2] + bi.z, v3 = acc2[mt][nf][3] + bi.w;
            ushort4 pk; pk.x = f2u(v0); pk.y = f2u(v1); pk.z = f2u(v2); pk.w = f2u(v3);
            *(ushort4*)(Y + n * 256 + ((g ^ (n & 7)) * 8 + e)) = pk;
            sj0 += v0; sj1 += v1; sj2 += v2; sj3 += v3;
            qj0 += v0 * v0; qj1 += v1 * v1; qj2 += v2 * v2; qj3 += v3 * v3;
        }
        #pragma unroll
        for (int m = 1; m <= 8; m <<= 1) {
            sj0 += __shfl_xor(sj0, m); sj1 += __shfl_xor(sj1, m);
            sj2 += __shfl_xor(sj2, m); sj3 += __shfl_xor(sj3, m);
            qj0 += __shfl_xor(qj0, m); qj1 += __shfl_xor(qj1, m);
            qj2 += __shfl_xor(qj2, m); qj3 += __shfl_xor(qj3, m);
        }
        if (r == 0) {
            stat[ob + 0] = sj0; stat[ob + 1] = sj1;
            stat[ob + 2] = sj2; stat[ob + 3] = sj3;
            stat[256 + ob + 0] = qj0; stat[256 + ob + 1] = qj1;
            stat[256 + ob + 2] = qj2; stat[256 + ob + 3] = qj3;
        }
    }
    __syncthreads();
    if (t < 256) {
        atomicAdd(&sums[512 + t], stat[t]);
        atomicAdd(&sums[768 + t], stat[256 + t]);
    }
    __threadfence();
    __syncthreads();
    // ---- grid barrier 2 ----
    if (t == 0) {
        __hip_atomic_fetch_add(&ctrs[16], 1u, __ATOMIC_ACQ_REL,
                               __HIP_MEMORY_SCOPE_AGENT);
        while (__hip_atomic_load(&ctrs[16], __ATOMIC_ACQUIRE,
                                 __HIP_MEMORY_SCOPE_AGENT) < 512u)
            __builtin_amdgcn_s_sleep(8);
    }
    __syncthreads();
    __threadfence();

    // ---- BN2 coefficients + BN2+ReLU + transpose -> out [B,256,N] fp32 ----
    if (t < 256) {
        float sv = __hip_atomic_load(&sums[512 + t], __ATOMIC_RELAXED,
                                     __HIP_MEMORY_SCOPE_AGENT);
        float qv = __hip_atomic_load(&sums[768 + t], __ATOMIC_RELAXED,
                                     __HIP_MEMORY_SCOPE_AGENT);
        float mean = sv * (1.f / 32768.f);
        float var = qv * (1.f / 32768.f) - mean * mean;
        float rstd = rsqrtf(var + 1e-5f);
        float sc = g2[t] * rstd;
        aux[t] = sc;
        aux[256 + t] = be2[t] - mean * sc;
    }
    __syncthreads();

    for (int pass = 0; pass < 4; ++pass) {
        int c0l = pass * 64;
        {
            int n = t >> 3, g8 = t & 7, g = (c0l >> 3) + g8;
            union { short8 s; ushort u[8]; } v;
            v.s = ld8(Y + n * 256 + ((g ^ (n & 7)) * 8));
            #pragma unroll
            for (int j = 0; j < 8; ++j)
                tl2[n * 65 + g8 * 8 + j] =
                    fmaxf(u2f(v.u[j]) * aux[g * 8 + j] + aux[256 + g * 8 + j], 0.f);
        }
        __syncthreads();
        {
            const int cl = t >> 4, n4 = (t & 15) * 4;     // cl 0..31
            #pragma unroll
            for (int it = 0; it < 2; ++it) {
                int c = cl + 32 * it;
                float4 v;
                v.x = tl2[(n4 + 0) * 65 + c];
                v.y = tl2[(n4 + 1) * 65 + c];
                v.z = tl2[(n4 + 2) * 65 + c];
                v.w = tl2[(n4 + 3) * 65 + c];
                *(float4*)(out + ((size_t)b * 256 + c0l + c) * N + n0 + n4) = v;
            }
        }
        __syncthreads();
    }
}

// ------------------------------------------------------------ launch -----
extern "C" void kernel_launch(void* const* d_in, const int* in_sizes, int n_in,
                              void* d_out, int out_size, void* d_ws, size_t ws_size,
                              hipStream_t stream)
{
    (void)in_sizes; (void)n_in; (void)out_size;
    if (ws_size < (16u << 20)) return;

    const float* pos1 = (const float*)d_in[0];
    const float* pos2 = (const float*)d_in[1];
    const float* f1   = (const float*)d_in[2];
    const float* f2   = (const float*)d_in[3];
    const float* W1   = (const float*)d_in[4];
    const float* b1   = (const float*)d_in[5];
    const float* g1   = (const float*)d_in[6];
    const float* be1  = (const float*)d_in[7];
    const float* W2   = (const float*)d_in[8];
    const float* b2   = (const float*)d_in[9];
    const float* g2   = (const float*)d_in[10];
    const float* be2  = (const float*)d_in[11];

    char* ws = (char*)d_ws;
    float*    sums = (float*)ws;                           // 1024 f32
    unsigned* ctrs = (unsigned*)(ws + 4096);               // 2 ctrs, 64B apart
    int*    idxb   = (int*)(ws + 8192);                    // 384 KB
    float*  wgt    = (float*)(ws + 8192 + 393216);         // 384 KB
    ushort* W1r    = (ushort*)(ws + 8192 + 786432);        // 192 KB
    ushort* W2r    = (ushort*)(ws + 8192 + 786432 + 196608); // 128 KB
    ushort* f2T    = (ushort*)(ws + (2u << 20));           // 4 MB
    ushort* f1T    = (ushort*)(ws + (6u << 20));           // 8 MB

    prep_all<<<1323, 512, 0, stream>>>(W1, W2, pos2, f2, f1, pos1,
                                       W1r, W2r, sums, f2T, f1T, wgt, idxb);

    mega_kernel<<<dim3(N / 64, B), 512, 0, stream>>>(
        W1r, b1, f2T, f1T, idxb, wgt, sums, ctrs,
        g1, be1, W2r, b2, g2, be2, (float*)d_out);
}

// Round 10
// 184.670 us; speedup vs baseline: 2.4732x; 2.4732x over previous
//
#include <hip/hip_runtime.h>
#include <hip/hip_bf16.h>

constexpr int B = 4, N = 8192, S = 2048;

typedef __attribute__((ext_vector_type(8))) short short8;
typedef __attribute__((ext_vector_type(4))) float v4f;

__device__ inline float u2f(ushort u) {
    union { ushort u; __hip_bfloat16 h; } c; c.u = u; return __bfloat162float(c.h);
}
__device__ inline ushort f2u(float f) {
    union { ushort u; __hip_bfloat16 h; } c; c.h = __float2bfloat16(f); return c.u;
}
__device__ inline void async_lds16(const void* g, void* l) {
    __builtin_amdgcn_global_load_lds(
        (const __attribute__((address_space(1))) unsigned*)g,
        (__attribute__((address_space(3))) unsigned*)l, 16, 0, 0);
}
__device__ inline short8 ld8(const ushort* p) { return *(const short8*)p; }

// ---------------- prep_all: W pack + pos2 pack + zero sums + both transposes
__device__ inline void transpose_tile(
    const float* __restrict__ ip, ushort* __restrict__ op,
    int L, int C, int l0, int c0, int t, ushort (*tl)[66])
{
    const int lr = t & 63, cb = t >> 6;
    #pragma unroll
    for (int i = 0; i < 16; ++i) {
        int c = cb + 4 * i;
        tl[lr][c] = f2u(ip[(size_t)(c0 + c) * L + l0 + lr]);
    }
    __syncthreads();
    const int cp = t & 31, lrow = t >> 5;
    #pragma unroll
    for (int i = 0; i < 8; ++i) {
        int l = lrow + 8 * i;
        ushort2 v;
        v.x = tl[l][2 * cp]; v.y = tl[l][2 * cp + 1];
        *(ushort2*)(op + (size_t)(l0 + l) * C + c0 + 2 * cp) = v;
    }
}

__global__ __launch_bounds__(256) void prep_all(
    const float* __restrict__ W1, const float* __restrict__ W2,
    const float* __restrict__ pos2, const float* __restrict__ f2,
    const float* __restrict__ f1,
    ushort* __restrict__ W1r, ushort* __restrict__ W2r,
    float4* __restrict__ p2pack, float* __restrict__ zero_region,
    ushort* __restrict__ f2T, ushort* __restrict__ f1T)
{
    __shared__ ushort tl[64][66];
    const int bid = blockIdx.x;
    const int t = threadIdx.x;
    if (bid < 512) {                       // f2: [B,256,S] -> [B,S,256] bf16
        int b = bid >> 7, ct = (bid >> 5) & 3, st = bid & 31;
        transpose_tile(f2 + (size_t)b * 256 * S, f2T + (size_t)b * S * 256,
                       S, 256, st * 64, ct * 64, t, tl);
    } else if (bid < 1536) {               // f1: [B,128,N] -> [B,N,128] bf16
        int u = bid - 512;
        int b = u >> 8, ct = (u >> 7) & 1, lt = u & 127;
        transpose_tile(f1 + (size_t)b * 128 * N, f1T + (size_t)b * N * 128,
                       N, 128, lt * 64, ct * 64, t, tl);
    } else {
        int i = (bid - 1536) * 256 + t;
        if (i < 12288) {                   // W1 chunk-major bf16 pack
            int kk = i >> 10, qq = (i >> 8) & 3, o = i & 255;
            const float* src = W1 + o * 384 + kk * 32 + qq * 8;
            float4 a = *(const float4*)src, bb = *(const float4*)(src + 4);
            union { short8 s; ushort u[8]; } pk;
            pk.u[0]=f2u(a.x); pk.u[1]=f2u(a.y); pk.u[2]=f2u(a.z); pk.u[3]=f2u(a.w);
            pk.u[4]=f2u(bb.x); pk.u[5]=f2u(bb.y); pk.u[6]=f2u(bb.z); pk.u[7]=f2u(bb.w);
            *(short8*)(W1r + i * 8) = pk.s;
        } else if (i < 20480) {            // W2 pack
            int u = i - 12288;
            int kk = u >> 10, qq = (u >> 8) & 3, o = u & 255;
            const float* src = W2 + o * 256 + kk * 32 + qq * 8;
            float4 a = *(const float4*)src, bb = *(const float4*)(src + 4);
            union { short8 s; ushort u[8]; } pk;
            pk.u[0]=f2u(a.x); pk.u[1]=f2u(a.y); pk.u[2]=f2u(a.z); pk.u[3]=f2u(a.w);
            pk.u[4]=f2u(bb.x); pk.u[5]=f2u(bb.y); pk.u[6]=f2u(bb.z); pk.u[7]=f2u(bb.w);
            *(short8*)(W2r + u * 8) = pk.s;
        } else if (i < 21504) {            // zero sums1[512]+sums2[512]
            zero_region[i - 20480] = 0.f;
        } else if (i < 21504 + B * S) {    // pos2 pack as (x,y,z,|p|^2)
            int u = i - 21504;
            int b = u >> 11, s = u & (S - 1);
            float x = pos2[(b * 3 + 0) * S + s];
            float y = pos2[(b * 3 + 1) * S + s];
            float z = pos2[(b * 3 + 2) * S + s];
            p2pack[u] = make_float4(x, y, z, x * x + y * y + z * z);
        }
    }
}

// -------- knn_gemm1: fused 3-NN + interp staging + GEMM1 + stats ----------
// 512 thr (8 waves). knn: 8 waves x 256 candidates == baseline arithmetic.
// GEMM1: 8 waves x 32 output channels (mt<2). smem: Xs [0,48K), Wbuf
// [48K,80K). knn scratch at [64K,77.6K) = Wbuf buffer-1, dead before its
// first prefetch (kk=0, after staging consumed idx/wgt).
__global__ __launch_bounds__(512) void knn_gemm1(
    const float* __restrict__ pos1, const float4* __restrict__ p2pack,
    const ushort* __restrict__ W1r, const float* __restrict__ bias1,
    const ushort* __restrict__ f2T, const ushort* __restrict__ f1T,
    ushort* __restrict__ y, float* __restrict__ sums)
{
    __shared__ __align__(16) char smem[81920];
    ushort* Xs   = (ushort*)smem;
    ushort* Wbuf = (ushort*)(smem + 49152);
    float*  dL   = (float*)(smem + 65536);                 // 8*64*3 f32
    int*    iL   = (int*)  (smem + 65536 + 6144);          // 8*64*3 i32
    float*  wgtL = (float*)(smem + 65536 + 12288);         // 64*3
    int*    idxL = (int*)  (smem + 65536 + 13056);         // 64*3

    const int t = threadIdx.x;
    const int lane = t & 63;
    const int w = __builtin_amdgcn_readfirstlane(t >> 6);  // 0..7
    const int b = blockIdx.y;
    const int n0 = blockIdx.x * 64;
    const int q = lane >> 4, r = lane & 15, r7 = r & 7;

    // W1 chunk0 prefetch overlaps the knn phase (into Wbuf buffer 0)
    #pragma unroll
    for (int jj = 0; jj < 2; ++jj)
        async_lds16((const char*)W1r + jj * 8192 + t * 16,
                    (char*)Wbuf + jj * 8192 + w * 1024);

    // ---- 3-NN: 8 waves x 256 candidates, lanes = queries ----
    {
        const int qi = n0 + lane;
        const float x1 = pos1[(b * 3 + 0) * N + qi];
        const float y1 = pos1[(b * 3 + 1) * N + qi];
        const float z1 = pos1[(b * 3 + 2) * N + qi];
        const float t1 = x1 * x1 + y1 * y1 + z1 * z1;
        const float4* __restrict__ pp = p2pack + b * S + w * 256;
        float d0 = 3.4e38f, d1 = 3.4e38f, d2 = 3.4e38f;
        int i0 = 0x7fffffff, i1 = 0x7fffffff, i2 = 0x7fffffff;
        #pragma unroll 8
        for (int i = 0; i < 256; ++i) {
            float4 p = pp[i];                       // uniform -> s_load
            float dot = fmaf(x1, p.x, fmaf(y1, p.y, z1 * p.z));
            float dd = fmaf(-2.f, dot, t1) + p.w;
            int s = w * 256 + i;
            bool c0 = dd < d0, c1 = dd < d1, c2 = dd < d2;
            i2 = c1 ? i1 : (c2 ? s : i2);
            i1 = c0 ? i0 : (c1 ? s : i1);
            i0 = c0 ? s : i0;
            float nd1 = __builtin_amdgcn_fmed3f(dd, d0, d1);
            float nd2 = __builtin_amdgcn_fmed3f(dd, d1, d2);
            d0 = fminf(d0, dd);
            d1 = nd1; d2 = nd2;
        }
        int base = (w * 64 + lane) * 3;
        dL[base + 0] = d0; dL[base + 1] = d1; dL[base + 2] = d2;
        iL[base + 0] = i0; iL[base + 1] = i1; iL[base + 2] = i2;
    }
    __syncthreads();
    if (t < 64) {
        float f0 = dL[t*3+0], fv1 = dL[t*3+1], fv2 = dL[t*3+2];
        int   j0 = iL[t*3+0], j1 = iL[t*3+1], j2 = iL[t*3+2];
        #pragma unroll
        for (int c = 1; c < 8; ++c) {
            int cb = (c * 64 + t) * 3;
            #pragma unroll
            for (int k = 0; k < 3; ++k) {
                float d = dL[cb + k]; int id = iL[cb + k];
                bool l0 = (d < f0)  || (d == f0  && id < j0);
                bool l1 = (d < fv1) || (d == fv1 && id < j1);
                bool l2 = (d < fv2) || (d == fv2 && id < j2);
                if (l0)      { fv2 = fv1; j2 = j1; fv1 = f0; j1 = j0; f0 = d; j0 = id; }
                else if (l1) { fv2 = fv1; j2 = j1; fv1 = d; j1 = id; }
                else if (l2) { fv2 = d; j2 = id; }
            }
        }
        float w0 = 1.f / fmaxf(f0, 1e-10f);
        float w1 = 1.f / fmaxf(fv1, 1e-10f);
        float w2 = 1.f / fmaxf(fv2, 1e-10f);
        float inv = 1.f / (w0 + w1 + w2);
        j0 = ((unsigned)j0 < S) ? j0 : 0;
        j1 = ((unsigned)j1 < S) ? j1 : 0;
        j2 = ((unsigned)j2 < S) ? j2 : 0;
        wgtL[t*3+0] = w0 * inv; wgtL[t*3+1] = w1 * inv; wgtL[t*3+2] = w2 * inv;
        idxL[t*3+0] = j0; idxL[t*3+1] = j1; idxL[t*3+2] = j2;
    }
    __syncthreads();

    // ---- X staging: fused interp (idx/wgt from LDS) + f1 tile ----
    {
        const int lp = t & 31, ro = t >> 5;               // ro 0..15
        #pragma unroll
        for (int it = 0; it < 4; ++it) {
            int rr = ro + 16 * it;
            int s0 = idxL[rr*3+0], s1 = idxL[rr*3+1], s2 = idxL[rr*3+2];
            float w0 = wgtL[rr*3+0], w1 = wgtL[rr*3+1], w2 = wgtL[rr*3+2];
            union { short8 s; ushort u[8]; } a, c, d, o;
            a.s = ld8(f2T + ((size_t)b * S + s0) * 256 + 8 * lp);
            c.s = ld8(f2T + ((size_t)b * S + s1) * 256 + 8 * lp);
            d.s = ld8(f2T + ((size_t)b * S + s2) * 256 + 8 * lp);
            #pragma unroll
            for (int j = 0; j < 8; ++j)
                o.u[j] = f2u(w0 * u2f(a.u[j]) + w1 * u2f(c.u[j]) + w2 * u2f(d.u[j]));
            *(short8*)(Xs + rr * 384 + ((lp ^ (rr & 7)) * 8)) = o.s;
        }
    }
    {
        const int lp = t & 15, ro = t >> 4;               // ro 0..31
        #pragma unroll
        for (int it = 0; it < 2; ++it) {
            int rr = ro + 32 * it;
            short8 v = ld8(f1T + ((size_t)b * N + n0 + rr) * 128 + 8 * lp);
            int c = 32 + lp;
            *(short8*)(Xs + rr * 384 + ((c ^ (rr & 7)) * 8)) = v;
        }
    }
    __syncthreads();

    // ---- GEMM1 (K=384, 12 chunks), 8 waves x 32 channels ----
    v4f acc[2][4];
    #pragma unroll
    for (int mt = 0; mt < 2; ++mt)
        #pragma unroll
        for (int nf = 0; nf < 4; ++nf) acc[mt][nf] = (v4f){0.f, 0.f, 0.f, 0.f};

    for (int kk = 0; kk < 12; ++kk) {
        if (kk < 11) {
            const char* g = (const char*)W1r + (kk + 1) * 16384;
            char* l = (char*)Wbuf + ((kk + 1) & 1) * 16384;
            #pragma unroll
            for (int jj = 0; jj < 2; ++jj)
                async_lds16(g + jj * 8192 + t * 16, l + jj * 8192 + w * 1024);
        }
        const ushort* Wb = Wbuf + (kk & 1) * 8192;
        short8 af[2], bf[4];
        #pragma unroll
        for (int mt = 0; mt < 2; ++mt)
            af[mt] = ld8(Wb + q * 2048 + (w * 32 + mt * 16 + r) * 8);
        #pragma unroll
        for (int nf = 0; nf < 4; ++nf)
            bf[nf] = ld8(Xs + (nf * 16 + r) * 384 + (((kk * 4 + q) ^ r7) * 8));
        #pragma unroll
        for (int mt = 0; mt < 2; ++mt)
            #pragma unroll
            for (int nf = 0; nf < 4; ++nf)
                acc[mt][nf] = __builtin_amdgcn_mfma_f32_16x16x32_bf16(
                    af[mt], bf[nf], acc[mt][nf], 0, 0, 0);
        __syncthreads();
    }

    // ---- epilogue: y -> HBM, stats -> atomics ----
    float* statS = (float*)Xs;
    float* statQ = statS + 256;
    #pragma unroll
    for (int mt = 0; mt < 2; ++mt) {
        int ob = w * 32 + mt * 16 + q * 4;
        float4 bi = *(const float4*)(bias1 + ob);
        float sj0 = 0, sj1 = 0, sj2 = 0, sj3 = 0;
        float qj0 = 0, qj1 = 0, qj2 = 0, qj3 = 0;
        #pragma unroll
        for (int nf = 0; nf < 4; ++nf) {
            int n = n0 + nf * 16 + r;
            float v0 = acc[mt][nf][0] + bi.x, v1 = acc[mt][nf][1] + bi.y;
            float v2 = acc[mt][nf][2] + bi.z, v3 = acc[mt][nf][3] + bi.w;
            ushort4 pk; pk.x = f2u(v0); pk.y = f2u(v1); pk.z = f2u(v2); pk.w = f2u(v3);
            *(ushort4*)(y + ((size_t)b * N + n) * 256 + ob) = pk;
            sj0 += v0; sj1 += v1; sj2 += v2; sj3 += v3;
            qj0 += v0 * v0; qj1 += v1 * v1; qj2 += v2 * v2; qj3 += v3 * v3;
        }
        #pragma unroll
        for (int m = 1; m <= 8; m <<= 1) {
            sj0 += __shfl_xor(sj0, m); sj1 += __shfl_xor(sj1, m);
            sj2 += __shfl_xor(sj2, m); sj3 += __shfl_xor(sj3, m);
            qj0 += __shfl_xor(qj0, m); qj1 += __shfl_xor(qj1, m);
            qj2 += __shfl_xor(qj2, m); qj3 += __shfl_xor(qj3, m);
        }
        if (r == 0) {
            statS[ob + 0] = sj0; statS[ob + 1] = sj1;
            statS[ob + 2] = sj2; statS[ob + 3] = sj3;
            statQ[ob + 0] = qj0; statQ[ob + 1] = qj1;
            statQ[ob + 2] = qj2; statQ[ob + 3] = qj3;
        }
    }
    __syncthreads();
    if (t < 256) {
        atomicAdd(&sums[t], statS[t]);
        atomicAdd(&sums[256 + t], statQ[t]);
    }
}

// ------------------------ GEMM2 (BN1+ReLU on load, in-place, fused stats) --
__global__ __launch_bounds__(512) void gemm2_kernel(
    const ushort* __restrict__ Wr, const float* __restrict__ bias,
    const float* __restrict__ sums1, const float* __restrict__ g1,
    const float* __restrict__ be1,
    ushort* __restrict__ y, float* __restrict__ sums)
{
    __shared__ __align__(16) ushort Xs[64 * 256];      // 32 KB
    __shared__ __align__(16) ushort Wbuf[2 * 8192];    // 32 KB
    __shared__ float ssA[256], ssB[256];
    const int t = threadIdx.x;
    const int b = blockIdx.y;
    const int n0 = blockIdx.x * 64;
    const int w = t >> 6, lane = t & 63;
    const int q = lane >> 4, r = lane & 15, r7 = r & 7;

    {
        const char* g0 = (const char*)Wr;
        #pragma unroll
        for (int jj = 0; jj < 2; ++jj)
            async_lds16(g0 + jj * 8192 + t * 16,
                        (char*)Wbuf + jj * 8192 + w * 1024);
    }

    if (t < 256) {
        float sv = sums1[t], qv = sums1[256 + t];
        float mean = sv * (1.f / 32768.f);
        float var = qv * (1.f / 32768.f) - mean * mean;
        float rstd = rsqrtf(var + 1e-5f);
        float sc = g1[t] * rstd;
        ssA[t] = sc;
        ssB[t] = be1[t] - mean * sc;
    }
    __syncthreads();

    {
        const int lp = t & 31, ro = t >> 5;               // ro 0..15
        #pragma unroll
        for (int it = 0; it < 4; ++it) {
            int rr = ro + 16 * it;
            union { short8 s; ushort u[8]; } v, o;
            v.s = ld8(y + ((size_t)b * N + n0 + rr) * 256 + 8 * lp);
            #pragma unroll
            for (int j = 0; j < 8; ++j)
                o.u[j] = f2u(fmaxf(u2f(v.u[j]) * ssA[8 * lp + j] + ssB[8 * lp + j], 0.f));
            *(short8*)(Xs + rr * 256 + ((lp ^ (rr & 7)) * 8)) = o.s;
        }
    }
    __syncthreads();

    v4f acc[2][4];
    #pragma unroll
    for (int mt = 0; mt < 2; ++mt)
        #pragma unroll
        for (int nf = 0; nf < 4; ++nf) acc[mt][nf] = (v4f){0.f, 0.f, 0.f, 0.f};

    for (int kk = 0; kk < 8; ++kk) {
        if (kk < 7) {
            const char* g = (const char*)Wr + (kk + 1) * 16384;
            char* l = (char*)Wbuf + ((kk + 1) & 1) * 16384;
            #pragma unroll
            for (int jj = 0; jj < 2; ++jj)
                async_lds16(g + jj * 8192 + t * 16, l + jj * 8192 + w * 1024);
        }
        const ushort* Wb = Wbuf + (kk & 1) * 8192;
        short8 af[2], bf[4];
        #pragma unroll
        for (int mt = 0; mt < 2; ++mt)
            af[mt] = ld8(Wb + q * 2048 + (w * 32 + mt * 16 + r) * 8);
        #pragma unroll
        for (int nf = 0; nf < 4; ++nf)
            bf[nf] = ld8(Xs + (nf * 16 + r) * 256 + (((kk * 4 + q) ^ r7) * 8));
        #pragma unroll
        for (int mt = 0; mt < 2; ++mt)
            #pragma unroll
            for (int nf = 0; nf < 4; ++nf)
                acc[mt][nf] = __builtin_amdgcn_mfma_f32_16x16x32_bf16(
                    af[mt], bf[nf], acc[mt][nf], 0, 0, 0);
        __syncthreads();
    }

    float* statS = (float*)Xs;
    float* statQ = statS + 256;
    #pragma unroll
    for (int mt = 0; mt < 2; ++mt) {
        int ob = w * 32 + mt * 16 + q * 4;
        float4 bi = *(const float4*)(bias + ob);
        float sj0 = 0, sj1 = 0, sj2 = 0, sj3 = 0;
        float qj0 = 0, qj1 = 0, qj2 = 0, qj3 = 0;
        #pragma unroll
        for (int nf = 0; nf < 4; ++nf) {
            int n = n0 + nf * 16 + r;
            float v0 = acc[mt][nf][0] + bi.x, v1 = acc[mt][nf][1] + bi.y;
            float v2 = acc[mt][nf][2] + bi.z, v3 = acc[mt][nf][3] + bi.w;
            ushort4 pk; pk.x = f2u(v0); pk.y = f2u(v1); pk.z = f2u(v2); pk.w = f2u(v3);
            *(ushort4*)(y + ((size_t)b * N + n) * 256 + ob) = pk;
            sj0 += v0; sj1 += v1; sj2 += v2; sj3 += v3;
            qj0 += v0 * v0; qj1 += v1 * v1; qj2 += v2 * v2; qj3 += v3 * v3;
        }
        #pragma unroll
        for (int m = 1; m <= 8; m <<= 1) {
            sj0 += __shfl_xor(sj0, m); sj1 += __shfl_xor(sj1, m);
            sj2 += __shfl_xor(sj2, m); sj3 += __shfl_xor(sj3, m);
            qj0 += __shfl_xor(qj0, m); qj1 += __shfl_xor(qj1, m);
            qj2 += __shfl_xor(qj2, m); qj3 += __shfl_xor(qj3, m);
        }
        if (r == 0) {
            statS[ob + 0] = sj0; statS[ob + 1] = sj1;
            statS[ob + 2] = sj2; statS[ob + 3] = sj3;
            statQ[ob + 0] = qj0; statQ[ob + 1] = qj1;
            statQ[ob + 2] = qj2; statQ[ob + 3] = qj3;
        }
    }
    __syncthreads();
    if (t < 256) {
        atomicAdd(&sums[t], statS[t]);
        atomicAdd(&sums[256 + t], statQ[t]);
    }
}

// ------------- final: BN2+ReLU + transpose to [B,256,N] fp32 (64x64) ------
__global__ __launch_bounds__(256) void final_kernel(
    const ushort* __restrict__ Y, const float* __restrict__ sums2,
    const float* __restrict__ g2, const float* __restrict__ be2,
    float* __restrict__ out)
{
    __shared__ float tl[64][65];
    __shared__ float ssA[64], ssB[64];
    const int t = threadIdx.x;
    const int b = blockIdx.z;
    const int n0 = blockIdx.x * 64, c0 = blockIdx.y * 64;

    if (t < 64) {
        int c = c0 + t;
        float sv = sums2[c], qv = sums2[256 + c];
        float mean = sv * (1.f / 32768.f);
        float var = qv * (1.f / 32768.f) - mean * mean;
        float rstd = rsqrtf(var + 1e-5f);
        float sc = g2[c] * rstd;
        ssA[t] = sc;
        ssB[t] = be2[c] - mean * sc;
    }
    __syncthreads();

    const int nl = t >> 3, cho = 8 * (t & 7);
    #pragma unroll
    for (int it = 0; it < 2; ++it) {
        int n = nl + 32 * it;
        union { short8 s; ushort u[8]; } v;
        v.s = ld8(Y + ((size_t)b * N + n0 + n) * 256 + c0 + cho);
        #pragma unroll
        for (int j = 0; j < 8; ++j)
            tl[n][cho + j] = fmaxf(u2f(v.u[j]) * ssA[cho + j] + ssB[cho + j], 0.f);
    }
    __syncthreads();

    const int cl = t >> 4, n4 = (t & 15) * 4;
    #pragma unroll
    for (int it = 0; it < 4; ++it) {
        int c = cl + 16 * it;
        float4 v;
        v.x = tl[n4 + 0][c]; v.y = tl[n4 + 1][c];
        v.z = tl[n4 + 2][c]; v.w = tl[n4 + 3][c];
        *(float4*)(out + ((size_t)b * 256 + c0 + c) * N + n0 + n4) = v;
    }
}

// ------------------------------------------------------------ launch -----
extern "C" void kernel_launch(void* const* d_in, const int* in_sizes, int n_in,
                              void* d_out, int out_size, void* d_ws, size_t ws_size,
                              hipStream_t stream)
{
    (void)in_sizes; (void)n_in; (void)out_size;
    if (ws_size < (30u << 20)) return;

    const float* pos1 = (const float*)d_in[0];
    const float* pos2 = (const float*)d_in[1];
    const float* f1   = (const float*)d_in[2];
    const float* f2   = (const float*)d_in[3];
    const float* W1   = (const float*)d_in[4];
    const float* b1   = (const float*)d_in[5];
    const float* g1   = (const float*)d_in[6];
    const float* be1  = (const float*)d_in[7];
    const float* W2   = (const float*)d_in[8];
    const float* b2   = (const float*)d_in[9];
    const float* g2   = (const float*)d_in[10];
    const float* be2  = (const float*)d_in[11];

    char* ws = (char*)d_ws;
    float*  sums1  = (float*)ws;                               // 512 f32
    float*  sums2  = sums1 + 512;                              // 512 f32
    ushort* W1r    = (ushort*)(ws + 4096);                     // 192 KB
    ushort* W2r    = (ushort*)(ws + 4096 + 196608);            // 128 KB
    float4* p2pack = (float4*)(ws + 4096 + 196608 + 131072);   // 128 KB
    ushort* f2T    = (ushort*)(ws + (1u << 19));               // 4 MB
    ushort* f1T    = (ushort*)(ws + (1u << 19) + (4u << 20));  // 8 MB
    ushort* y      = (ushort*)(ws + (1u << 19) + (12u << 20)); // 16 MB

    prep_all<<<1652, 256, 0, stream>>>(W1, W2, pos2, f2, f1,
                                       W1r, W2r, p2pack, sums1, f2T, f1T);

    knn_gemm1<<<dim3(N / 64, B), 512, 0, stream>>>(
        pos1, p2pack, W1r, b1, f2T, f1T, y, sums1);

    gemm2_kernel<<<dim3(N / 64, B), 512, 0, stream>>>(
        W2r, b2, sums1, g1, be1, y, sums2);

    final_kernel<<<dim3(N / 64, 256 / 64, B), 256, 0, stream>>>(
        y, sums2, g2, be2, (float*)d_out);
}